// Round 9
// baseline (200.981 us; speedup 1.0000x reference)
//
#include <hip/hip_runtime.h>
#include <math.h>

// GraphConvolution (GCNII variant=True, residual=True), N=100k, E=1M, D=64.
//   agg[dst] += h[src] * edge_w
//   out = theta*([agg,i]@W) + (1-theta)*((1-alpha)*agg + alpha*i) + i
//
// R9 (from R8): node-degree histogram moved into bin_fill (global int
// atomics); spmm drops its hist pass (one less bucket read + barrier round),
// gather loads predicated (was ~38% wasted on clamped dead slots), node loop
// restructured for cross-node pipelining.
// LESSON (R3+R7): LDS f32 atomicAdd is catastrophic -- register-accumulate.

#define DFEAT 64
#define BINSZ 128        // nodes per bin
#define NBINS 1024       // physical; logical = ceil(N/128) = 782
#define CAP   2048       // slots per bucket (mean 1280, sigma ~36)
#define CHUNK 4096       // edges per bin_fill block
#define TPB   512
#define ASTR  72         // agg16 row stride in ushorts (144 B, 16B-aligned)

typedef unsigned long long u64;
typedef __attribute__((ext_vector_type(8))) short bf16x8;
typedef __attribute__((ext_vector_type(4))) float f32x4;

__device__ inline unsigned short to_bf16(float f) {   // RNE
    unsigned u = __float_as_uint(f);
    u += 0x7FFF + ((u >> 16) & 1);
    return (unsigned short)(u >> 16);
}
__device__ inline float bf_up(unsigned short s) {
    return __uint_as_float(((unsigned)s) << 16);
}

// ---- phase 1: cvt h + pack W + deg hist + bin edges by dst>>7 ----
// Entry: low32 = src | (dstLocal<<24) (dl < 128), high32 = bits(w).
__global__ __launch_bounds__(512) void bin_fill_kernel(
    const float* __restrict__ h, const float* __restrict__ weight,
    const int* __restrict__ e_src, const int* __restrict__ e_dst,
    const float* __restrict__ e_w, int* __restrict__ gcur,
    int* __restrict__ deg, u64* __restrict__ bucket,
    ushort* __restrict__ h16, ushort* __restrict__ w16, int E, int total4) {
    __shared__ u64 staging[CHUNK];            // 32 KB
    __shared__ unsigned short binOf[CHUNK];   // 8 KB
    __shared__ int hist[NBINS], offs[NBINS], gbase[NBINS], cur[NBINS]; // 16 KB
    __shared__ int part[TPB];                 // 2 KB

    int tid = threadIdx.x;
    int gid = blockIdx.x * TPB + tid;
    int nthreads = gridDim.x * TPB;

    // 0a: h (fp32) -> h16 (bf16), grid-stride over ushort4 groups
    for (int i = gid; i < total4; i += nthreads) {
        float4 v = ((const float4*)h)[i];
        ushort4 o;
        o.x = to_bf16(v.x); o.y = to_bf16(v.y);
        o.z = to_bf16(v.z); o.w = to_bf16(v.w);
        ((ushort4*)h16)[i] = o;
    }
    // 0b: W -> frag-packed bf16: w16[((c*4+s)*64+l)*8+j]
    //     = bf16(W[s*32 + (l>>4)*8 + j][c*16 + (l&15)])
    if (gid < 8192) {
        int j = gid & 7, l = (gid >> 3) & 63, cs = gid >> 9;
        int c = cs >> 2, s = cs & 3, q = l >> 4, m = l & 15;
        w16[gid] = to_bf16(weight[(s * 32 + q * 8 + j) * DFEAT + c * 16 + m]);
    }

    int e0 = blockIdx.x * CHUNK;
    int cc = min(CHUNK, E - e0);

    hist[tid] = 0; hist[tid + 512] = 0;
    __syncthreads();

    int d[8], s[8];
    float w[8];
#pragma unroll
    for (int j = 0; j < 8; ++j) {
        int e = e0 + j * TPB + tid;
        if (e < E) { d[j] = e_dst[e]; s[j] = e_src[e]; w[j] = e_w[e]; }
        else d[j] = -1;
    }
#pragma unroll
    for (int j = 0; j < 8; ++j)
        if (d[j] >= 0) {
            atomicAdd(&hist[d[j] >> 7], 1);
            atomicAdd(&deg[d[j]], 1);       // global per-node degree
        }
    __syncthreads();

    // exclusive scan of hist[1024]: thread t owns pair (2t, 2t+1)
    int a = hist[2 * tid], b = hist[2 * tid + 1];
    part[tid] = a + b;
    __syncthreads();
    for (int ofs = 1; ofs < TPB; ofs <<= 1) {
        int t = (tid >= ofs) ? part[tid - ofs] : 0;
        __syncthreads();
        part[tid] += t;
        __syncthreads();
    }
    int excl = part[tid] - (a + b);
    offs[2 * tid] = excl;         cur[2 * tid] = excl;
    offs[2 * tid + 1] = excl + a; cur[2 * tid + 1] = excl + a;
    __syncthreads();

    // scatter into bin-sorted LDS staging
#pragma unroll
    for (int j = 0; j < 8; ++j) {
        if (d[j] >= 0) {
            int bb = d[j] >> 7;
            int p = atomicAdd(&cur[bb], 1);
            unsigned lo = (unsigned)s[j] | ((unsigned)(d[j] & 127) << 24);
            staging[p] = ((u64)(unsigned)__float_as_int(w[j]) << 32) | lo;
            binOf[p] = (unsigned short)bb;
        }
    }
    __syncthreads();

    // reserve global space: one atomic per non-empty bin
    for (int t = tid; t < NBINS; t += TPB) {
        int c = hist[t];
        gbase[t] = (c > 0) ? atomicAdd(&gcur[t], c) : 0;
    }
    __syncthreads();

    // flush: bin-contiguous runs -> contiguous global slots
#pragma unroll
    for (int j = 0; j < 8; ++j) {
        int p = j * TPB + tid;
        if (p < cc) {
            int bb = binOf[p];
            bucket[(size_t)bb * CAP + gbase[bb] + (p - offs[bb])] = staging[p];
        }
    }
}

// ---- phase 2: per-bin sort + register-accumulate gather + MFMA epilogue ----
// 512 threads (8 waves), ~37 KB LDS -> 4 blocks/CU. Wave wv gathers nodes
// [wv*16, wv*16+16) then runs the MFMA epilogue for that same tile.
__global__ __launch_bounds__(512) void spmm_kernel(
    const ushort* __restrict__ h16, const u64* __restrict__ bucket,
    const int* __restrict__ gcur, const int* __restrict__ deg,
    const ushort* __restrict__ w16, const float* __restrict__ ifeat,
    const float* __restrict__ lamda_p, const float* __restrict__ alpha_p,
    const int* __restrict__ layer_p,
    float* __restrict__ out, int N) {
    __shared__ u64 sorted[CAP];                          // 16 KB
    __shared__ __align__(16) ushort agg16[BINSZ * ASTR]; // 18 KB (bf16 agg)
    __shared__ int dsh[BINSZ], start[BINSZ], cur[BINSZ], part[BINSZ]; // 2 KB

    int tid = threadIdx.x;
    int bin = blockIdx.x;
    int base = bin << 7;
    int cnt = gcur[bin];
    const u64* bk = bucket + (size_t)bin * CAP;

    // load per-node degrees (computed by bin_fill) + exclusive scan
    int v = 0;
    if (tid < BINSZ) {
        v = (base + tid < N) ? deg[base + tid] : 0;
        dsh[tid] = v; part[tid] = v;
    }
    __syncthreads();
    for (int ofs = 1; ofs < BINSZ; ofs <<= 1) {
        int t = (tid < BINSZ && tid >= ofs) ? part[tid - ofs] : 0;
        __syncthreads();
        if (tid < BINSZ) part[tid] += t;
        __syncthreads();
    }
    if (tid < BINSZ) { start[tid] = part[tid] - v; cur[tid] = part[tid] - v; }
    __syncthreads();

    // permute into node-sorted LDS: batch loads, then LDS int atomics
    {
        u64 e[4]; int pp[4], np = 0;
#pragma unroll
        for (int j = 0; j < 4; ++j) {
            int p = tid + j * TPB;
            if (p < cnt) { e[np] = bk[p]; pp[np] = p; ++np; }
        }
        for (int j = 0; j < np; ++j) {
            int pos = atomicAdd(&cur[(((unsigned)e[j]) >> 24) & 127], 1);
            sorted[pos] = e[j];
        }
        (void)pp;
    }
    __syncthreads();

    int lane = tid & 63, wv = tid >> 6;
    int g = lane >> 4, m = lane & 15;
    int nn = min(BINSZ, N - base);

    // gather: quad g owns edge t0+s*4+g, lane covers features m*4..m*4+3.
    int kmax = min(16, nn - wv * 16);
    for (int k = 0; k < kmax; ++k) {
        int nl = wv * 16 + k;
        int d = dsh[nl];
        int b0 = start[nl];
        float a0 = 0.f, a1 = 0.f, a2 = 0.f, a3 = 0.f;
        for (int t0 = 0; t0 < d; t0 += 16) {
#pragma unroll
            for (int s = 0; s < 4; ++s) {
                int idx = t0 + s * 4 + g;
                if (idx < d) {                       // exec-masked: no dead loads
                    u64 e = sorted[b0 + idx];
                    float wt = __int_as_float((int)(e >> 32));
                    int src = ((unsigned)e) & 0xFFFFFF;
                    ushort4 hv = *(const ushort4*)(h16 + (size_t)src * DFEAT + m * 4);
                    a0 += wt * bf_up(hv.x);
                    a1 += wt * bf_up(hv.y);
                    a2 += wt * bf_up(hv.z);
                    a3 += wt * bf_up(hv.w);
                }
            }
        }
        a0 += __shfl_xor(a0, 16); a1 += __shfl_xor(a1, 16);
        a2 += __shfl_xor(a2, 16); a3 += __shfl_xor(a3, 16);
        a0 += __shfl_xor(a0, 32); a1 += __shfl_xor(a1, 32);
        a2 += __shfl_xor(a2, 32); a3 += __shfl_xor(a3, 32);
        if (g == 0) {
            ushort4 o;
            o.x = to_bf16(a0); o.y = to_bf16(a1);
            o.z = to_bf16(a2); o.w = to_bf16(a3);
            *(ushort4*)(agg16 + nl * ASTR + m * 4) = o;
        }
    }

    // fused epilogue for tile rows [wv*16, wv*16+16) -- same-wave data only.
    float alf = alpha_p[0];
    float theta = fminf(1.0f, logf(lamda_p[0] / (float)layer_p[0] + 1.0f));
    int q = lane >> 4;

    bf16x8 faA[2], faI[2];
#pragma unroll
    for (int s = 0; s < 2; ++s)
        faA[s] = *(const bf16x8*)(agg16 + (wv * 16 + m) * ASTR + s * 32 + q * 8);
    {
        const float* ip = ifeat + (size_t)min(base + wv * 16 + m, N - 1) * DFEAT;
#pragma unroll
        for (int s = 0; s < 2; ++s) {
            float4 v0 = *(const float4*)(ip + s * 32 + q * 8);
            float4 v1 = *(const float4*)(ip + s * 32 + q * 8 + 4);
            bf16x8 t;
            t[0] = (short)to_bf16(v0.x); t[1] = (short)to_bf16(v0.y);
            t[2] = (short)to_bf16(v0.z); t[3] = (short)to_bf16(v0.w);
            t[4] = (short)to_bf16(v1.x); t[5] = (short)to_bf16(v1.y);
            t[6] = (short)to_bf16(v1.z); t[7] = (short)to_bf16(v1.w);
            faI[s] = t;
        }
    }

    f32x4 acc[4] = {{0.f, 0.f, 0.f, 0.f}, {0.f, 0.f, 0.f, 0.f},
                    {0.f, 0.f, 0.f, 0.f}, {0.f, 0.f, 0.f, 0.f}};
#pragma unroll
    for (int c = 0; c < 4; ++c) {
#pragma unroll
        for (int s = 0; s < 2; ++s) {
            bf16x8 bA = *(const bf16x8*)(w16 + ((c * 4 + s) * 64 + lane) * 8);
            acc[c] = __builtin_amdgcn_mfma_f32_16x16x32_bf16(faA[s], bA, acc[c], 0, 0, 0);
            bf16x8 bI = *(const bf16x8*)(w16 + ((c * 4 + s + 2) * 64 + lane) * 8);
            acc[c] = __builtin_amdgcn_mfma_f32_16x16x32_bf16(faI[s], bI, acc[c], 0, 0, 0);
        }
    }

    // mix + residual + store (C/D: row = wv*16 + q*4 + r, col = c*16 + m)
#pragma unroll
    for (int c = 0; c < 4; ++c) {
        int col = c * 16 + m;
#pragma unroll
        for (int r = 0; r < 4; ++r) {
            int rowL = wv * 16 + q * 4 + r;
            int row = base + rowL;
            if (row < N) {
                float av = bf_up(agg16[rowL * ASTR + col]);
                float iv = ifeat[(size_t)row * DFEAT + col];
                out[(size_t)row * DFEAT + col] =
                    theta * acc[c][r] +
                    (1.f - theta) * ((1.f - alf) * av + alf * iv) + iv;
            }
        }
    }
}

extern "C" void kernel_launch(void* const* d_in, const int* in_sizes, int n_in,
                              void* d_out, int out_size, void* d_ws, size_t ws_size,
                              hipStream_t stream) {
    const float* h       = (const float*)d_in[0];
    const float* ifeat   = (const float*)d_in[1];
    const float* weight  = (const float*)d_in[2];
    const float* edge_w  = (const float*)d_in[3];
    const float* lamda_p = (const float*)d_in[4];
    const float* alpha_p = (const float*)d_in[5];
    const int*   e_src   = (const int*)d_in[6];
    const int*   e_dst   = (const int*)d_in[7];
    const int*   layer_p = (const int*)d_in[8];
    float* out = (float*)d_out;

    int N = in_sizes[0] / DFEAT;       // 100000
    int E = in_sizes[3];               // 1000000
    int nbins = (N + BINSZ - 1) >> 7;  // 782

    // ws: gcur[1024] | deg[N] | (align) | bucket 16.78MB | h16 12.8MB | w16 16KB
    int* gcur = (int*)d_ws;
    int* deg = gcur + NBINS;
    size_t degbytes = (size_t)(NBINS + N) * sizeof(int);
    size_t bucket_off = (degbytes + 4095) & ~(size_t)4095;
    u64* bucket = (u64*)((char*)d_ws + bucket_off);
    ushort* h16 = (ushort*)((char*)bucket + (size_t)NBINS * CAP * sizeof(u64));
    ushort* w16 = h16 + (size_t)N * DFEAT;

    // zero gcur + deg in one memset
    hipMemsetAsync(gcur, 0, degbytes, stream);

    int total4 = N * DFEAT / 4;
    bin_fill_kernel<<<(E + CHUNK - 1) / CHUNK, TPB, 0, stream>>>(
        h, weight, e_src, e_dst, edge_w, gcur, deg, bucket, h16, w16, E, total4);

    spmm_kernel<<<nbins, TPB, 0, stream>>>(
        h16, bucket, gcur, deg, w16, ifeat, lamda_p, alpha_p, layer_p, out, N);
}

// Round 10
// 164.745 us; speedup vs baseline: 1.2200x; 1.2200x over previous
//
#include <hip/hip_runtime.h>
#include <math.h>

// GraphConvolution (GCNII variant=True, residual=True), N=100k, E=1M, D=64.
//   agg[dst] += h[src] * edge_w
//   out = theta*([agg,i]@W) + (1-theta)*((1-alpha)*agg + alpha*i) + i
//
// R10 (from R8; R9's global deg atomics reverted -- +18us regression):
//   bin_fill: shfl-based scan (18 barriers -> 2).
//   spmm: bucket read ONCE into registers; rank = atomicAdd(hist) return
//         value -> permute is one pass, no cur[], no second bucket read.
// LESSON (R3+R7): LDS f32 atomicAdd is catastrophic -- register-accumulate.

#define DFEAT 64
#define BINSZ 128        // nodes per bin
#define NBINS 1024       // physical; logical = ceil(N/128) = 782
#define CAP   2048       // slots per bucket (mean 1280, sigma ~36)
#define CHUNK 4096       // edges per bin_fill block
#define TPB   512
#define ASTR  72         // agg16 row stride in ushorts (144 B, 16B-aligned)

typedef unsigned long long u64;
typedef __attribute__((ext_vector_type(8))) short bf16x8;
typedef __attribute__((ext_vector_type(4))) float f32x4;

__device__ inline unsigned short to_bf16(float f) {   // RNE
    unsigned u = __float_as_uint(f);
    u += 0x7FFF + ((u >> 16) & 1);
    return (unsigned short)(u >> 16);
}
__device__ inline float bf_up(unsigned short s) {
    return __uint_as_float(((unsigned)s) << 16);
}

// ---- phase 1: cvt h + pack W + bin edges by dst>>7 into global buckets ----
// Entry: low32 = src | (dstLocal<<24) (dl < 128), high32 = bits(w).
__global__ __launch_bounds__(512) void bin_fill_kernel(
    const float* __restrict__ h, const float* __restrict__ weight,
    const int* __restrict__ e_src, const int* __restrict__ e_dst,
    const float* __restrict__ e_w, int* __restrict__ gcur,
    u64* __restrict__ bucket, ushort* __restrict__ h16,
    ushort* __restrict__ w16, int E, int total4) {
    __shared__ u64 staging[CHUNK];            // 32 KB
    __shared__ unsigned short binOf[CHUNK];   // 8 KB
    __shared__ int hist[NBINS], offs[NBINS], gbase[NBINS], cur[NBINS]; // 16 KB
    __shared__ int wsum[8];

    int tid = threadIdx.x;
    int gid = blockIdx.x * TPB + tid;
    int nthreads = gridDim.x * TPB;
    int lane = tid & 63, wv = tid >> 6;

    // 0a: h (fp32) -> h16 (bf16), grid-stride over ushort4 groups
    for (int i = gid; i < total4; i += nthreads) {
        float4 v = ((const float4*)h)[i];
        ushort4 o;
        o.x = to_bf16(v.x); o.y = to_bf16(v.y);
        o.z = to_bf16(v.z); o.w = to_bf16(v.w);
        ((ushort4*)h16)[i] = o;
    }
    // 0b: W -> frag-packed bf16: w16[((c*4+s)*64+l)*8+j]
    //     = bf16(W[s*32 + (l>>4)*8 + j][c*16 + (l&15)])
    if (gid < 8192) {
        int j = gid & 7, l = (gid >> 3) & 63, cs = gid >> 9;
        int c = cs >> 2, s = cs & 3, q = l >> 4, m = l & 15;
        w16[gid] = to_bf16(weight[(s * 32 + q * 8 + j) * DFEAT + c * 16 + m]);
    }

    int e0 = blockIdx.x * CHUNK;
    int cc = min(CHUNK, E - e0);

    hist[tid] = 0; hist[tid + 512] = 0;
    __syncthreads();

    int d[8], s[8];
    float w[8];
#pragma unroll
    for (int j = 0; j < 8; ++j) {
        int e = e0 + j * TPB + tid;
        if (e < E) { d[j] = e_dst[e]; s[j] = e_src[e]; w[j] = e_w[e]; }
        else d[j] = -1;
    }
#pragma unroll
    for (int j = 0; j < 8; ++j)
        if (d[j] >= 0) atomicAdd(&hist[d[j] >> 7], 1);
    __syncthreads();

    // exclusive scan of hist[1024]: thread owns pair (2t,2t+1); shfl scan
    int a = hist[2 * tid], b = hist[2 * tid + 1];
    int x = a + b;
    int xs = x;
#pragma unroll
    for (int o = 1; o < 64; o <<= 1) {
        int t = __shfl_up(xs, o);
        if (lane >= o) xs += t;
    }
    if (lane == 63) wsum[wv] = xs;
    __syncthreads();
    if (tid == 0) {
        int r = 0;
#pragma unroll
        for (int i = 0; i < 8; ++i) { int t = wsum[i]; wsum[i] = r; r += t; }
    }
    __syncthreads();
    int excl = xs - x + wsum[wv];
    offs[2 * tid] = excl;         cur[2 * tid] = excl;
    offs[2 * tid + 1] = excl + a; cur[2 * tid + 1] = excl + a;
    __syncthreads();

    // scatter into bin-sorted LDS staging
#pragma unroll
    for (int j = 0; j < 8; ++j) {
        if (d[j] >= 0) {
            int bb = d[j] >> 7;
            int p = atomicAdd(&cur[bb], 1);
            unsigned lo = (unsigned)s[j] | ((unsigned)(d[j] & 127) << 24);
            staging[p] = ((u64)(unsigned)__float_as_int(w[j]) << 32) | lo;
            binOf[p] = (unsigned short)bb;
        }
    }
    __syncthreads();

    // reserve global space: one atomic per non-empty bin
    for (int t = tid; t < NBINS; t += TPB) {
        int c = hist[t];
        gbase[t] = (c > 0) ? atomicAdd(&gcur[t], c) : 0;
    }
    __syncthreads();

    // flush: bin-contiguous runs -> contiguous global slots
#pragma unroll
    for (int j = 0; j < 8; ++j) {
        int p = j * TPB + tid;
        if (p < cc) {
            int bb = binOf[p];
            bucket[(size_t)bb * CAP + gbase[bb] + (p - offs[bb])] = staging[p];
        }
    }
}

// ---- phase 2: per-bin sort + register-accumulate gather + MFMA epilogue ----
// 512 threads (8 waves), ~36 KB LDS -> 4 blocks/CU, 32 VGPR target.
// Bucket read ONCE: entries live in registers; hist atomic gives the rank.
// Wave wv gathers nodes [wv*16, wv*16+16) then runs that tile's epilogue.
__global__ __launch_bounds__(512) void spmm_kernel(
    const ushort* __restrict__ h16, const u64* __restrict__ bucket,
    const int* __restrict__ gcur, const ushort* __restrict__ w16,
    const float* __restrict__ ifeat,
    const float* __restrict__ lamda_p, const float* __restrict__ alpha_p,
    const int* __restrict__ layer_p,
    float* __restrict__ out, int N) {
    __shared__ u64 sorted[CAP];                          // 16 KB
    __shared__ __align__(16) ushort agg16[BINSZ * ASTR]; // 18 KB (bf16 agg)
    __shared__ int hist[BINSZ], start[BINSZ];            // 1 KB
    __shared__ int wsum2;

    int tid = threadIdx.x;
    int bin = blockIdx.x;
    int base = bin << 7;
    int cnt = gcur[bin];
    const u64* bk = bucket + (size_t)bin * CAP;

    // load this thread's bucket entries ONCE
    u64 e[4]; int np = 0;
#pragma unroll
    for (int j = 0; j < 4; ++j) {
        int p = tid + j * TPB;
        if (p < cnt) { e[np] = bk[p]; ++np; }
    }

    if (tid < BINSZ) hist[tid] = 0;
    __syncthreads();

    // histogram; the atomic's return value IS the within-node rank
    int rk[4], dl[4];
    for (int j = 0; j < np; ++j) {
        dl[j] = (((unsigned)e[j]) >> 24) & 127;
        rk[j] = atomicAdd(&hist[dl[j]], 1);
    }
    __syncthreads();

    // exclusive scan of hist[128] (2 waves, shfl-based)
    int lane = tid & 63, wv = tid >> 6;
    if (tid < BINSZ) {
        int v = hist[tid];
        int xs = v;
#pragma unroll
        for (int o = 1; o < 64; o <<= 1) {
            int t = __shfl_up(xs, o);
            if (lane >= o) xs += t;
        }
        if (tid == 63) wsum2 = xs;
        start[tid] = xs - v;    // wave-local exclusive
    }
    __syncthreads();
    if (tid >= 64 && tid < BINSZ) start[tid] += wsum2;
    __syncthreads();

    // permute from registers into node-sorted LDS
    for (int j = 0; j < np; ++j)
        sorted[start[dl[j]] + rk[j]] = e[j];
    __syncthreads();

    int g = lane >> 4, m = lane & 15;
    int nn = min(BINSZ, N - base);

    // gather: quad g owns edge t0+s*4+g, lane covers features m*4..m*4+3.
    int kmax = min(16, nn - wv * 16);
    for (int k = 0; k < kmax; ++k) {
        int nl = wv * 16 + k;
        int d = hist[nl];
        int b0 = start[nl];
        float a0 = 0.f, a1 = 0.f, a2 = 0.f, a3 = 0.f;
        for (int t0 = 0; t0 < d; t0 += 16) {
#pragma unroll
            for (int s = 0; s < 4; ++s) {
                int idx = t0 + s * 4 + g;
                if (idx < d) {                       // exec-masked: no dead loads
                    u64 ee = sorted[b0 + idx];
                    float wt = __int_as_float((int)(ee >> 32));
                    int src = ((unsigned)ee) & 0xFFFFFF;
                    ushort4 hv = *(const ushort4*)(h16 + (size_t)src * DFEAT + m * 4);
                    a0 += wt * bf_up(hv.x);
                    a1 += wt * bf_up(hv.y);
                    a2 += wt * bf_up(hv.z);
                    a3 += wt * bf_up(hv.w);
                }
            }
        }
        a0 += __shfl_xor(a0, 16); a1 += __shfl_xor(a1, 16);
        a2 += __shfl_xor(a2, 16); a3 += __shfl_xor(a3, 16);
        a0 += __shfl_xor(a0, 32); a1 += __shfl_xor(a1, 32);
        a2 += __shfl_xor(a2, 32); a3 += __shfl_xor(a3, 32);
        if (g == 0) {
            ushort4 o;
            o.x = to_bf16(a0); o.y = to_bf16(a1);
            o.z = to_bf16(a2); o.w = to_bf16(a3);
            *(ushort4*)(agg16 + nl * ASTR + m * 4) = o;
        }
    }

    // fused epilogue for tile rows [wv*16, wv*16+16) -- same-wave data only.
    float alf = alpha_p[0];
    float theta = fminf(1.0f, logf(lamda_p[0] / (float)layer_p[0] + 1.0f));
    int q = lane >> 4;

    bf16x8 faA[2], faI[2];
#pragma unroll
    for (int s = 0; s < 2; ++s)
        faA[s] = *(const bf16x8*)(agg16 + (wv * 16 + m) * ASTR + s * 32 + q * 8);
    {
        const float* ip = ifeat + (size_t)min(base + wv * 16 + m, N - 1) * DFEAT;
#pragma unroll
        for (int s = 0; s < 2; ++s) {
            float4 v0 = *(const float4*)(ip + s * 32 + q * 8);
            float4 v1 = *(const float4*)(ip + s * 32 + q * 8 + 4);
            bf16x8 t;
            t[0] = (short)to_bf16(v0.x); t[1] = (short)to_bf16(v0.y);
            t[2] = (short)to_bf16(v0.z); t[3] = (short)to_bf16(v0.w);
            t[4] = (short)to_bf16(v1.x); t[5] = (short)to_bf16(v1.y);
            t[6] = (short)to_bf16(v1.z); t[7] = (short)to_bf16(v1.w);
            faI[s] = t;
        }
    }

    f32x4 acc[4] = {{0.f, 0.f, 0.f, 0.f}, {0.f, 0.f, 0.f, 0.f},
                    {0.f, 0.f, 0.f, 0.f}, {0.f, 0.f, 0.f, 0.f}};
#pragma unroll
    for (int c = 0; c < 4; ++c) {
#pragma unroll
        for (int s = 0; s < 2; ++s) {
            bf16x8 bA = *(const bf16x8*)(w16 + ((c * 4 + s) * 64 + lane) * 8);
            acc[c] = __builtin_amdgcn_mfma_f32_16x16x32_bf16(faA[s], bA, acc[c], 0, 0, 0);
            bf16x8 bI = *(const bf16x8*)(w16 + ((c * 4 + s + 2) * 64 + lane) * 8);
            acc[c] = __builtin_amdgcn_mfma_f32_16x16x32_bf16(faI[s], bI, acc[c], 0, 0, 0);
        }
    }

    // mix + residual + store (C/D: row = wv*16 + q*4 + r, col = c*16 + m)
#pragma unroll
    for (int c = 0; c < 4; ++c) {
        int col = c * 16 + m;
#pragma unroll
        for (int r = 0; r < 4; ++r) {
            int rowL = wv * 16 + q * 4 + r;
            int row = base + rowL;
            if (row < N) {
                float av = bf_up(agg16[rowL * ASTR + col]);
                float iv = ifeat[(size_t)row * DFEAT + col];
                out[(size_t)row * DFEAT + col] =
                    theta * acc[c][r] +
                    (1.f - theta) * ((1.f - alf) * av + alf * iv) + iv;
            }
        }
    }
}

extern "C" void kernel_launch(void* const* d_in, const int* in_sizes, int n_in,
                              void* d_out, int out_size, void* d_ws, size_t ws_size,
                              hipStream_t stream) {
    const float* h       = (const float*)d_in[0];
    const float* ifeat   = (const float*)d_in[1];
    const float* weight  = (const float*)d_in[2];
    const float* edge_w  = (const float*)d_in[3];
    const float* lamda_p = (const float*)d_in[4];
    const float* alpha_p = (const float*)d_in[5];
    const int*   e_src   = (const int*)d_in[6];
    const int*   e_dst   = (const int*)d_in[7];
    const int*   layer_p = (const int*)d_in[8];
    float* out = (float*)d_out;

    int N = in_sizes[0] / DFEAT;       // 100000
    int E = in_sizes[3];               // 1000000
    int nbins = (N + BINSZ - 1) >> 7;  // 782

    // ws: gcur[1024] (4KB) | bucket 16.78MB | h16 12.8MB | w16 16KB
    int* gcur = (int*)d_ws;
    u64* bucket = (u64*)((char*)d_ws + 4096);
    ushort* h16 = (ushort*)((char*)bucket + (size_t)NBINS * CAP * sizeof(u64));
    ushort* w16 = h16 + (size_t)N * DFEAT;

    hipMemsetAsync(gcur, 0, NBINS * sizeof(int), stream);

    int total4 = N * DFEAT / 4;
    bin_fill_kernel<<<(E + CHUNK - 1) / CHUNK, TPB, 0, stream>>>(
        h, weight, e_src, e_dst, edge_w, gcur, bucket, h16, w16, E, total4);

    spmm_kernel<<<nbins, TPB, 0, stream>>>(
        h16, bucket, gcur, w16, ifeat, lamda_p, alpha_p, layer_p, out, N);
}